// Round 3
// baseline (341.454 us; speedup 1.0000x reference)
//
#include <hip/hip_runtime.h>

typedef __bf16 bf16;
typedef __bf16 bf16x8 __attribute__((ext_vector_type(8)));
typedef float f32x4 __attribute__((ext_vector_type(4)));

#define NB    2048
#define NM    26
#define NROWS 65536   // (b,k) pairs

// ---------------- prep kernels: fp32 -> bf16 with layout reorder ----------------

// xb[(b*32+k)*32 + j] = inputs[b][j][k]  (j>=26 -> 0)
__global__ __launch_bounds__(256) void prep_x(const float* __restrict__ in, bf16* __restrict__ xb) {
  int e = blockIdx.x * 256 + threadIdx.x;
  int row = e >> 5, j = e & 31;
  int b = row >> 5, k = row & 31;
  float v = (j < NM) ? in[b*(NM*32) + j*32 + k] : 0.f;
  xb[e] = (bf16)v;
}

// w1r[h][c*32+i] = W1[h][i][c]   (i>=26 -> 0); inner dim 832
__global__ __launch_bounds__(256) void prep_w1(const float* __restrict__ w, bf16* __restrict__ wr) {
  int e = blockIdx.x * 256 + threadIdx.x;
  int h = e / 832, r = e - h*832;
  int j = r >> 5, i = r & 31;
  float v = (i < NM) ? w[h*(NM*NM) + i*NM + j] : 0.f;
  wr[e] = (bf16)v;
}

// w2r[h][j*128+i] = W2[h][i][j]; inner dim 3328
__global__ __launch_bounds__(256) void prep_w2(const float* __restrict__ w, bf16* __restrict__ wr) {
  int e = blockIdx.x * 256 + threadIdx.x;
  int h = e / 3328, r = e - h*3328;
  int j = r >> 7, i = r & 127;
  wr[e] = (bf16)w[h*(128*NM) + i*NM + j];
}

// ---------------- layer 1: barrier-free register K-loop -----------------------
// 4096 waves; wave tile 32 rows x 64 cols; K = 26 chunks of 32.
// A[row][c*32+i] = x0[row][c]*x0[row][i]
__global__ __launch_bounds__(256) void cin1(
    const bf16* __restrict__ xb, const bf16* __restrict__ w1r,
    const float* __restrict__ b1, bf16* __restrict__ x1b,
    float* __restrict__ out)
{
  const int t = threadIdx.x;
  const int lane = t & 63, w = t >> 6;
  const int gw = blockIdx.x * 4 + w;
  const int strip = gw >> 1, cs = (gw & 1) * 64;
  const int rowBase = strip * 32;
  const int lr = lane & 15, lq = lane >> 4;

  // x0 slice in registers: rows mi*16+lr, cols lq*8..+8 (f32 for cheap A-build)
  float xf[2][8];
  #pragma unroll
  for (int mi = 0; mi < 2; ++mi) {
    bf16x8 xr = *(const bf16x8*)&xb[(rowBase + mi*16 + lr)*32 + lq*8];
    #pragma unroll
    for (int e = 0; e < 8; ++e) xf[mi][e] = (float)xr[e];
  }

  f32x4 acc[2][4];
  #pragma unroll
  for (int mi=0; mi<2; ++mi)
    #pragma unroll
    for (int ni=0; ni<4; ++ni) acc[mi][ni] = {0.f,0.f,0.f,0.f};

  const bf16* bp = w1r + (cs + lr)*832 + lq*8;   // + ni*16*832 + c*32
  bf16x8 bc[4], bn[4];
  float scc[2], scn[2];
  #pragma unroll
  for (int ni=0; ni<4; ++ni) bc[ni] = *(const bf16x8*)(bp + ni*13312);
  #pragma unroll
  for (int mi=0; mi<2; ++mi) scc[mi] = (float)xb[(rowBase + mi*16 + lr)*32];

  for (int c = 0; c < 26; ++c) {
    if (c < 25) {
      #pragma unroll
      for (int ni=0; ni<4; ++ni) bn[ni] = *(const bf16x8*)(bp + ni*13312 + (c+1)*32);
      #pragma unroll
      for (int mi=0; mi<2; ++mi) scn[mi] = (float)xb[(rowBase + mi*16 + lr)*32 + c + 1];
    }
    bf16x8 af[2];
    #pragma unroll
    for (int mi=0; mi<2; ++mi)
      #pragma unroll
      for (int e=0; e<8; ++e) af[mi][e] = (bf16)(scc[mi] * xf[mi][e]);
    #pragma unroll
    for (int mi=0; mi<2; ++mi)
      #pragma unroll
      for (int ni=0; ni<4; ++ni)
        acc[mi][ni] = __builtin_amdgcn_mfma_f32_16x16x32_bf16(af[mi], bc[ni], acc[mi][ni], 0, 0, 0);
    #pragma unroll
    for (int ni=0; ni<4; ++ni) bc[ni] = bn[ni];
    scc[0] = scn[0]; scc[1] = scn[1];
  }

  float bias[4];
  #pragma unroll
  for (int ni=0; ni<4; ++ni) bias[ni] = b1[cs + ni*16 + lr];
  #pragma unroll
  for (int mi=0; mi<2; ++mi)
    #pragma unroll
    for (int ni=0; ni<4; ++ni) {
      int col = cs + ni*16 + lr;
      #pragma unroll
      for (int r=0; r<4; ++r) {
        int row = rowBase + mi*16 + lq*4 + r;
        x1b[row*128 + col] = (bf16)(acc[mi][ni][r] + bias[ni]);
      }
    }
  // out[b][col] = sum over all 32 k-rows + 32*bias
  const int b = rowBase >> 5;
  #pragma unroll
  for (int ni=0; ni<4; ++ni) {
    float v = 0.f;
    #pragma unroll
    for (int mi=0; mi<2; ++mi)
      #pragma unroll
      for (int r=0; r<4; ++r) v += acc[mi][ni][r];
    v += __shfl_xor(v, 16, 64);
    v += __shfl_xor(v, 32, 64);
    if (lq == 0) out[b*256 + cs + ni*16 + lr] = v + 32.0f * bias[ni];
  }
}

// ---------------- layer 2: barrier-free, split-K x4 ---------------------------
// 8192 waves; wave tile 64 rows x 64 cols x (ii quarter of K).
// chunk (j,ii): A[row][kk] = x0[row][j] * x1[row][ii*32+kk]
__global__ __launch_bounds__(256) void cin2(
    const bf16* __restrict__ xb, const bf16* __restrict__ x1b,
    const bf16* __restrict__ w2r, float* __restrict__ p2)
{
  const int t = threadIdx.x;
  const int lane = t & 63, w = t >> 6;
  const int gw = blockIdx.x * 4 + w;
  const int strip = gw >> 3;
  const int rem = gw & 7, cs = (rem & 1) * 64, ii = rem >> 1;
  const int rowBase = strip * 64;
  const int lr = lane & 15, lq = lane >> 4;

  // x1 slice in registers (bf16): rows mi*16+lr, cols ii*32 + lq*8..+8
  bf16x8 xr[4];
  #pragma unroll
  for (int mi = 0; mi < 4; ++mi)
    xr[mi] = *(const bf16x8*)&x1b[(rowBase + mi*16 + lr)*128 + ii*32 + lq*8];

  f32x4 acc[4][4];
  #pragma unroll
  for (int mi=0; mi<4; ++mi)
    #pragma unroll
    for (int ni=0; ni<4; ++ni) acc[mi][ni] = {0.f,0.f,0.f,0.f};

  const bf16* bp = w2r + (cs + lr)*3328 + ii*32 + lq*8;  // + ni*16*3328 + j*128
  bf16x8 bc[4], bn[4];
  float scc[4], scn[4];
  #pragma unroll
  for (int ni=0; ni<4; ++ni) bc[ni] = *(const bf16x8*)(bp + ni*53248);
  #pragma unroll
  for (int mi=0; mi<4; ++mi) scc[mi] = (float)xb[(rowBase + mi*16 + lr)*32];

  for (int j = 0; j < 26; ++j) {
    if (j < 25) {
      #pragma unroll
      for (int ni=0; ni<4; ++ni) bn[ni] = *(const bf16x8*)(bp + ni*53248 + (j+1)*128);
      #pragma unroll
      for (int mi=0; mi<4; ++mi) scn[mi] = (float)xb[(rowBase + mi*16 + lr)*32 + j + 1];
    }
    bf16x8 af[4];
    #pragma unroll
    for (int mi=0; mi<4; ++mi)
      #pragma unroll
      for (int e=0; e<8; ++e) af[mi][e] = (bf16)(scc[mi] * (float)xr[mi][e]);
    #pragma unroll
    for (int mi=0; mi<4; ++mi)
      #pragma unroll
      for (int ni=0; ni<4; ++ni)
        acc[mi][ni] = __builtin_amdgcn_mfma_f32_16x16x32_bf16(af[mi], bc[ni], acc[mi][ni], 0, 0, 0);
    #pragma unroll
    for (int ni=0; ni<4; ++ni) bc[ni] = bn[ni];
    #pragma unroll
    for (int mi=0; mi<4; ++mi) scc[mi] = scn[mi];
  }

  // epilogue: 64 rows = 2 b-groups; partial k-sums to p2[ii][b][col]
  const int b0 = rowBase >> 5;
  #pragma unroll
  for (int half=0; half<2; ++half) {
    #pragma unroll
    for (int ni=0; ni<4; ++ni) {
      float v = 0.f;
      #pragma unroll
      for (int mi=0; mi<2; ++mi)
        #pragma unroll
        for (int r=0; r<4; ++r) v += acc[half*2+mi][ni][r];
      v += __shfl_xor(v, 16, 64);
      v += __shfl_xor(v, 32, 64);
      if (lq == 0) p2[(ii*NB + b0 + half)*128 + cs + ni*16 + lr] = v;
    }
  }
}

// ---------------- combine: out[b][128+col] = sum_ii p2 + 32*b2 ----------------
__global__ __launch_bounds__(256) void combine(
    const float* __restrict__ p2, const float* __restrict__ b2, float* __restrict__ out)
{
  int idx = blockIdx.x * 256 + threadIdx.x;   // [0, NB*128)
  int b = idx >> 7, col = idx & 127;
  float v = 32.0f * b2[col];
  #pragma unroll
  for (int ii=0; ii<4; ++ii) v += p2[(ii*NB + b)*128 + col];
  out[b*256 + 128 + col] = v;
}

// ---------------- launch ----------------
extern "C" void kernel_launch(void* const* d_in, const int* in_sizes, int n_in,
                              void* d_out, int out_size, void* d_ws, size_t ws_size,
                              hipStream_t stream) {
  const float* in = (const float*)d_in[0];
  const float* W1 = (const float*)d_in[1];
  const float* b1 = (const float*)d_in[2];
  const float* W2 = (const float*)d_in[3];
  const float* b2 = (const float*)d_in[4];
  float* out = (float*)d_out;

  char* ws = (char*)d_ws;
  bf16*  xb  = (bf16*)(ws);               // 65536*32*2   = 4   MiB
  bf16*  w1r = (bf16*)(ws + 4194304);     // 128*832*2    = 208 KiB
  bf16*  w2r = (bf16*)(ws + 4407296);     // 128*3328*2   = 832 KiB
  bf16*  x1b = (bf16*)(ws + 5259264);     // 65536*128*2  = 16  MiB
  float* p2  = (float*)(ws + 22036480);   // 4*2048*128*4 = 4   MiB

  prep_x <<<NROWS*32/256, 256, 0, stream>>>(in, xb);
  prep_w1<<<128*832/256,  256, 0, stream>>>(W1, w1r);
  prep_w2<<<128*3328/256, 256, 0, stream>>>(W2, w2r);
  cin1   <<<1024,         256, 0, stream>>>(xb, w1r, b1, x1b, out);
  cin2   <<<2048,         256, 0, stream>>>(xb, x1b, w2r, p2);
  combine<<<NB*128/256,   256, 0, stream>>>(p2, b2, out);
}

// Round 4
// 257.640 us; speedup vs baseline: 1.3253x; 1.3253x over previous
//
#include <hip/hip_runtime.h>

typedef __bf16 bf16;
typedef __bf16 bf16x8 __attribute__((ext_vector_type(8)));
typedef float f32x4 __attribute__((ext_vector_type(4)));

#define NB    2048
#define NM    26
#define NROWS 65536   // (b,k) pairs

__device__ __forceinline__ void gl_lds16(const bf16* g, bf16* l) {
  __builtin_amdgcn_global_load_lds(
      (const __attribute__((address_space(1))) void*)g,
      (__attribute__((address_space(3))) void*)l, 16, 0, 0);
}

// stage one 64x32 bf16 B-chunk (rows stride `stride` elems) into per-wave LDS
__device__ __forceinline__ void stage_chunk(const bf16* gsrc, bf16* lbase, int lane, int stride) {
  const int h4 = lane >> 2, s8 = (lane & 3) * 8;
  #pragma unroll
  for (int p = 0; p < 4; ++p)
    gl_lds16(gsrc + (p*16 + h4)*stride + s8, lbase + p*512 + lane*8);
}

// ---------------- prep kernels: fp32 -> bf16 with layout reorder ----------------

// xb[(b*32+k)*32 + j] = inputs[b][j][k]  (j>=26 -> 0)
__global__ __launch_bounds__(256) void prep_x(const float* __restrict__ in, bf16* __restrict__ xb) {
  int e = blockIdx.x * 256 + threadIdx.x;
  int row = e >> 5, j = e & 31;
  int b = row >> 5, k = row & 31;
  float v = (j < NM) ? in[b*(NM*32) + j*32 + k] : 0.f;
  xb[e] = (bf16)v;
}

// w1r[h][c*32+i] = W1[h][i][c]   (i>=26 -> 0); inner dim 832
__global__ __launch_bounds__(256) void prep_w1(const float* __restrict__ w, bf16* __restrict__ wr) {
  int e = blockIdx.x * 256 + threadIdx.x;
  int h = e / 832, r = e - h*832;
  int j = r >> 5, i = r & 31;
  float v = (i < NM) ? w[h*(NM*NM) + i*NM + j] : 0.f;
  wr[e] = (bf16)v;
}

// w2r[h][j*128+i] = W2[h][i][j]; inner dim 3328
__global__ __launch_bounds__(256) void prep_w2(const float* __restrict__ w, bf16* __restrict__ wr) {
  int e = blockIdx.x * 256 + threadIdx.x;
  int h = e / 3328, r = e - h*3328;
  int j = r >> 7, i = r & 127;
  wr[e] = (bf16)w[h*(128*NM) + i*NM + j];
}

// ---------------- layer 1: no barriers, per-wave LDS B-staging ----------------
// 2048 waves; wave tile 64 rows x 64 cols; K = 26 chunks of 32.
// A[row][c*32+i] = x0[row][c]*x0[row][i]
__global__ __launch_bounds__(256, 4) void cin1(
    const bf16* __restrict__ xb, const bf16* __restrict__ w1r,
    const float* __restrict__ b1, bf16* __restrict__ x1b,
    float* __restrict__ out)
{
  __shared__ __align__(16) bf16 ldsB[4][2][2048];   // [wave][buf][64x32]
  const int t = threadIdx.x;
  const int lane = t & 63, w = t >> 6;
  const int gw = blockIdx.x * 4 + w;
  const int strip = gw >> 1, cs = (gw & 1) * 64;
  const int rowBase = strip * 64;
  const int lr = lane & 15, lq = lane >> 4;
  bf16* myB = &ldsB[w][0][0];
  const bf16* wbase = w1r + (long)cs * 832;

  // x0 slice in registers: rows mi*16+lr, cols lq*8..+8
  bf16x8 xr[4];
  #pragma unroll
  for (int mi = 0; mi < 4; ++mi)
    xr[mi] = *(const bf16x8*)&xb[(rowBase + mi*16 + lr)*32 + lq*8];

  f32x4 acc[4][4];
  #pragma unroll
  for (int mi=0; mi<4; ++mi)
    #pragma unroll
    for (int ni=0; ni<4; ++ni) acc[mi][ni] = {0.f,0.f,0.f,0.f};

  float scc[4], scn[4];
  #pragma unroll
  for (int mi=0; mi<4; ++mi) scc[mi] = (float)xb[(rowBase + mi*16 + lr)*32];

  stage_chunk(wbase, myB, lane, 832);

  int buf = 0;
  for (int c = 0; c < 26; ++c) {
    bf16x8 bfr[4];
    #pragma unroll
    for (int ni=0; ni<4; ++ni)
      bfr[ni] = *(const bf16x8*)&myB[buf*2048 + (ni*16+lr)*32 + lq*8];
    if (c < 25) {
      stage_chunk(wbase + (c+1)*32, myB + (buf^1)*2048, lane, 832);
      #pragma unroll
      for (int mi=0; mi<4; ++mi) scn[mi] = (float)xb[(rowBase + mi*16 + lr)*32 + c + 1];
    }
    bf16x8 af[4];
    #pragma unroll
    for (int mi=0; mi<4; ++mi)
      #pragma unroll
      for (int e=0; e<8; ++e) af[mi][e] = (bf16)(scc[mi] * (float)xr[mi][e]);
    #pragma unroll
    for (int mi=0; mi<4; ++mi)
      #pragma unroll
      for (int ni=0; ni<4; ++ni)
        acc[mi][ni] = __builtin_amdgcn_mfma_f32_16x16x32_bf16(af[mi], bfr[ni], acc[mi][ni], 0, 0, 0);
    #pragma unroll
    for (int mi=0; mi<4; ++mi) scc[mi] = scn[mi];
    buf ^= 1;
  }

  float bias[4];
  #pragma unroll
  for (int ni=0; ni<4; ++ni) bias[ni] = b1[cs + ni*16 + lr];
  #pragma unroll
  for (int mi=0; mi<4; ++mi)
    #pragma unroll
    for (int ni=0; ni<4; ++ni) {
      int col = cs + ni*16 + lr;
      #pragma unroll
      for (int r=0; r<4; ++r) {
        int row = rowBase + mi*16 + lq*4 + r;
        x1b[row*128 + col] = (bf16)(acc[mi][ni][r] + bias[ni]);
      }
    }
  // out[b][col] = sum_k x1 + 32*bias; 64 rows = 2 b's
  #pragma unroll
  for (int half=0; half<2; ++half) {
    int b = (rowBase >> 5) + half;
    #pragma unroll
    for (int ni=0; ni<4; ++ni) {
      float v = 0.f;
      #pragma unroll
      for (int mi=0; mi<2; ++mi)
        #pragma unroll
        for (int r=0; r<4; ++r) v += acc[half*2+mi][ni][r];
      v += __shfl_xor(v, 16, 64);
      v += __shfl_xor(v, 32, 64);
      if (lq == 0) out[b*256 + cs + ni*16 + lr] = v + 32.0f * bias[ni];
    }
  }
}

// ---------------- layer 2: no barriers, per-wave staging, split-K x4 ----------
// 8192 waves; wave tile 64 rows x 64 cols x (ii quarter of K).
// chunk (j,ii): A[row][kk] = x0[row][j] * x1[row][ii*32+kk]
__global__ __launch_bounds__(256, 4) void cin2(
    const bf16* __restrict__ xb, const bf16* __restrict__ x1b,
    const bf16* __restrict__ w2r, float* __restrict__ p2)
{
  __shared__ __align__(16) bf16 ldsB[4][2][2048];
  const int t = threadIdx.x;
  const int lane = t & 63, w = t >> 6;
  const int gw = blockIdx.x * 4 + w;
  const int strip = gw >> 3;
  const int rem = gw & 7, cs = (rem & 1) * 64, ii = rem >> 1;
  const int rowBase = strip * 64;
  const int lr = lane & 15, lq = lane >> 4;
  bf16* myB = &ldsB[w][0][0];
  const bf16* wbase = w2r + (long)cs * 3328 + ii*32;   // + j*128 per chunk

  // x1 slice in registers: rows mi*16+lr, cols ii*32 + lq*8..+8
  bf16x8 xr[4];
  #pragma unroll
  for (int mi = 0; mi < 4; ++mi)
    xr[mi] = *(const bf16x8*)&x1b[(rowBase + mi*16 + lr)*128 + ii*32 + lq*8];

  f32x4 acc[4][4];
  #pragma unroll
  for (int mi=0; mi<4; ++mi)
    #pragma unroll
    for (int ni=0; ni<4; ++ni) acc[mi][ni] = {0.f,0.f,0.f,0.f};

  float scc[4], scn[4];
  #pragma unroll
  for (int mi=0; mi<4; ++mi) scc[mi] = (float)xb[(rowBase + mi*16 + lr)*32];

  stage_chunk(wbase, myB, lane, 3328);

  int buf = 0;
  for (int j = 0; j < 26; ++j) {
    bf16x8 bfr[4];
    #pragma unroll
    for (int ni=0; ni<4; ++ni)
      bfr[ni] = *(const bf16x8*)&myB[buf*2048 + (ni*16+lr)*32 + lq*8];
    if (j < 25) {
      stage_chunk(wbase + (j+1)*128, myB + (buf^1)*2048, lane, 3328);
      #pragma unroll
      for (int mi=0; mi<4; ++mi) scn[mi] = (float)xb[(rowBase + mi*16 + lr)*32 + j + 1];
    }
    bf16x8 af[4];
    #pragma unroll
    for (int mi=0; mi<4; ++mi)
      #pragma unroll
      for (int e=0; e<8; ++e) af[mi][e] = (bf16)(scc[mi] * (float)xr[mi][e]);
    #pragma unroll
    for (int mi=0; mi<4; ++mi)
      #pragma unroll
      for (int ni=0; ni<4; ++ni)
        acc[mi][ni] = __builtin_amdgcn_mfma_f32_16x16x32_bf16(af[mi], bfr[ni], acc[mi][ni], 0, 0, 0);
    #pragma unroll
    for (int mi=0; mi<4; ++mi) scc[mi] = scn[mi];
    buf ^= 1;
  }

  // partial k-sums to p2[ii][b][col]; 64 rows = 2 b's
  #pragma unroll
  for (int half=0; half<2; ++half) {
    int b = (rowBase >> 5) + half;
    #pragma unroll
    for (int ni=0; ni<4; ++ni) {
      float v = 0.f;
      #pragma unroll
      for (int mi=0; mi<2; ++mi)
        #pragma unroll
        for (int r=0; r<4; ++r) v += acc[half*2+mi][ni][r];
      v += __shfl_xor(v, 16, 64);
      v += __shfl_xor(v, 32, 64);
      if (lq == 0) p2[(ii*NB + b)*128 + cs + ni*16 + lr] = v;
    }
  }
}

// ---------------- combine: out[b][128+col] = sum_ii p2 + 32*b2 ----------------
__global__ __launch_bounds__(256) void combine(
    const float* __restrict__ p2, const float* __restrict__ b2, float* __restrict__ out)
{
  int idx = blockIdx.x * 256 + threadIdx.x;   // [0, NB*128)
  int b = idx >> 7, col = idx & 127;
  float v = 32.0f * b2[col];
  #pragma unroll
  for (int ii=0; ii<4; ++ii) v += p2[(ii*NB + b)*128 + col];
  out[b*256 + 128 + col] = v;
}

// ---------------- launch ----------------
extern "C" void kernel_launch(void* const* d_in, const int* in_sizes, int n_in,
                              void* d_out, int out_size, void* d_ws, size_t ws_size,
                              hipStream_t stream) {
  const float* in = (const float*)d_in[0];
  const float* W1 = (const float*)d_in[1];
  const float* b1 = (const float*)d_in[2];
  const float* W2 = (const float*)d_in[3];
  const float* b2 = (const float*)d_in[4];
  float* out = (float*)d_out;

  char* ws = (char*)d_ws;
  bf16*  xb  = (bf16*)(ws);               // 65536*32*2   = 4   MiB
  bf16*  w1r = (bf16*)(ws + 4194304);     // 128*832*2    = 208 KiB
  bf16*  w2r = (bf16*)(ws + 4407296);     // 128*3328*2   = 832 KiB
  bf16*  x1b = (bf16*)(ws + 5259264);     // 65536*128*2  = 16  MiB
  float* p2  = (float*)(ws + 22036480);   // 4*2048*128*4 = 4   MiB

  prep_x <<<NROWS*32/256, 256, 0, stream>>>(in, xb);
  prep_w1<<<128*832/256,  256, 0, stream>>>(W1, w1r);
  prep_w2<<<128*3328/256, 256, 0, stream>>>(W2, w2r);
  cin1   <<<512,          256, 0, stream>>>(xb, w1r, b1, x1b, out);
  cin2   <<<2048,         256, 0, stream>>>(xb, x1b, w2r, p2);
  combine<<<NB*128/256,   256, 0, stream>>>(p2, b2, out);
}

// Round 5
// 167.931 us; speedup vs baseline: 2.0333x; 1.5342x over previous
//
#include <hip/hip_runtime.h>

typedef __bf16 bf16;
typedef __bf16 bf16x8 __attribute__((ext_vector_type(8)));
typedef float f32x4 __attribute__((ext_vector_type(4)));

#define NB    2048
#define NM    26
#define NROWS 65536   // (b,k) pairs

// ---------------- prep kernels: fp32 -> bf16 with layout reorder ----------------

// xb[(b*32+k)*32 + j] = inputs[b][j][k]  (j>=26 -> 0)
__global__ __launch_bounds__(256) void prep_x(const float* __restrict__ in, bf16* __restrict__ xb) {
  int e = blockIdx.x * 256 + threadIdx.x;
  int row = e >> 5, j = e & 31;
  int b = row >> 5, k = row & 31;
  float v = (j < NM) ? in[b*(NM*32) + j*32 + k] : 0.f;
  xb[e] = (bf16)v;
}

// w1t: tiles [cs_idx(2)][c(26)] of [r(64)][i(32)]:  = W1[h=cs_idx*64+r][i][j=c] (i>=26 -> 0)
__global__ __launch_bounds__(256) void prep_w1t(const float* __restrict__ w, bf16* __restrict__ wt) {
  int e = blockIdx.x * 256 + threadIdx.x;     // [0, 2*26*2048)
  int i = e & 31, r = (e >> 5) & 63;
  int rest = e >> 11;                          // [0,52)
  int c = rest % 26, cs_idx = rest / 26;
  int h = cs_idx*64 + r;
  float v = (i < NM) ? w[h*(NM*NM) + i*NM + c] : 0.f;
  wt[e] = (bf16)v;
}

// w2t: tiles [cs_idx(2)][ii(4)][j(26)] of [r(64)][c(32)]: = W2[h=cs_idx*64+r][i=ii*32+c][j]
__global__ __launch_bounds__(256) void prep_w2t(const float* __restrict__ w, bf16* __restrict__ wt) {
  int e = blockIdx.x * 256 + threadIdx.x;     // [0, 2*4*26*2048)
  int c = e & 31, r = (e >> 5) & 63;
  int rest = e >> 11;                          // [0,208)
  int j = rest % 26, q = rest / 26;            // q = cs_idx*4 + ii
  int ii = q & 3, cs_idx = q >> 2;
  int h = cs_idx*64 + r, i = ii*32 + c;
  wt[e] = (bf16)w[h*(128*NM) + i*NM + j];
}

// ---------------- layer 1: register K-loop, coalesced tile B-loads ------------
// 512 blocks x 4 waves; wave tile 64 rows x 64 cols; block covers 128 rows.
// A[row][c*32+i] = x0[row][c]*x0[row][i]
__global__ __launch_bounds__(256, 3) void cin1(
    const bf16* __restrict__ xb, const bf16* __restrict__ w1t,
    const float* __restrict__ b1, bf16* __restrict__ x1b,
    float* __restrict__ out)
{
  __shared__ float xT[26][128];               // xT[j][r] = x0[rowBase0+r][j]
  const int t = threadIdx.x;
  const int lane = t & 63, w = t >> 6;
  const int rowBase0 = blockIdx.x * 128;
  const int strip = blockIdx.x*2 + (w >> 1);  // 64-row strip
  const int cs_idx = w & 1, cs = cs_idx * 64;
  const int rowBase = strip * 64;
  const int lr = lane & 15, lq = lane >> 4;
  const int rloc = (w >> 1)*64;               // strip offset within block LDS

  for (int idx = t; idx < 26*128; idx += 256) {
    int j = idx >> 7, r = idx & 127;
    xT[j][r] = (float)xb[(rowBase0 + r)*32 + j];
  }

  // x0 slice in f32 registers: rows mi*16+lr, cols lq*8..+8
  float xf[4][8];
  #pragma unroll
  for (int mi = 0; mi < 4; ++mi) {
    bf16x8 xr = *(const bf16x8*)&xb[(rowBase + mi*16 + lr)*32 + lq*8];
    #pragma unroll
    for (int e = 0; e < 8; ++e) xf[mi][e] = (float)xr[e];
  }

  f32x4 acc[4][4];
  #pragma unroll
  for (int mi=0; mi<4; ++mi)
    #pragma unroll
    for (int ni=0; ni<4; ++ni) acc[mi][ni] = {0.f,0.f,0.f,0.f};

  const bf16* tb = w1t + (long)cs_idx*26*2048 + (lr*32 + lq*8); // + c*2048 + ni*512
  bf16x8 bc[4], bn[4];
  float scc[4], scn[4];
  #pragma unroll
  for (int ni=0; ni<4; ++ni) bc[ni] = *(const bf16x8*)(tb + ni*512);

  __syncthreads();
  #pragma unroll
  for (int mi=0; mi<4; ++mi) scc[mi] = xT[0][rloc + mi*16 + lr];

  for (int c = 0; c < 26; ++c) {
    if (c < 25) {
      #pragma unroll
      for (int ni=0; ni<4; ++ni) bn[ni] = *(const bf16x8*)(tb + (c+1)*2048 + ni*512);
      #pragma unroll
      for (int mi=0; mi<4; ++mi) scn[mi] = xT[c+1][rloc + mi*16 + lr];
    }
    bf16x8 af[4];
    #pragma unroll
    for (int mi=0; mi<4; ++mi)
      #pragma unroll
      for (int e=0; e<8; ++e) af[mi][e] = (bf16)(scc[mi] * xf[mi][e]);
    #pragma unroll
    for (int mi=0; mi<4; ++mi)
      #pragma unroll
      for (int ni=0; ni<4; ++ni)
        acc[mi][ni] = __builtin_amdgcn_mfma_f32_16x16x32_bf16(af[mi], bc[ni], acc[mi][ni], 0, 0, 0);
    #pragma unroll
    for (int ni=0; ni<4; ++ni) bc[ni] = bn[ni];
    #pragma unroll
    for (int mi=0; mi<4; ++mi) scc[mi] = scn[mi];
  }

  float bias[4];
  #pragma unroll
  for (int ni=0; ni<4; ++ni) bias[ni] = b1[cs + ni*16 + lr];
  #pragma unroll
  for (int mi=0; mi<4; ++mi)
    #pragma unroll
    for (int ni=0; ni<4; ++ni) {
      int col = cs + ni*16 + lr;
      #pragma unroll
      for (int r=0; r<4; ++r) {
        int row = rowBase + mi*16 + lq*4 + r;
        x1b[row*128 + col] = (bf16)(acc[mi][ni][r] + bias[ni]);
      }
    }
  // out[b][col] = sum_k x1 + 32*bias; 64 rows = 2 b's
  #pragma unroll
  for (int half=0; half<2; ++half) {
    int b = (rowBase >> 5) + half;
    #pragma unroll
    for (int ni=0; ni<4; ++ni) {
      float v = 0.f;
      #pragma unroll
      for (int mi=0; mi<2; ++mi)
        #pragma unroll
        for (int r=0; r<4; ++r) v += acc[half*2+mi][ni][r];
      v += __shfl_xor(v, 16, 64);
      v += __shfl_xor(v, 32, 64);
      if (lq == 0) out[b*256 + cs + ni*16 + lr] = v + 32.0f * bias[ni];
    }
  }
}

// ---------------- layer 2: register K-loop, split-K x4 ------------------------
// 2048 blocks x 4 waves; block = (strip, cs_half); wave w = ii quarter.
// chunk (j,ii): A[row][kk] = x0[row][j] * x1[row][ii*32+kk]
__global__ __launch_bounds__(256, 3) void cin2(
    const bf16* __restrict__ xb, const bf16* __restrict__ x1b,
    const bf16* __restrict__ w2t, float* __restrict__ p2)
{
  __shared__ float xT[26][64];                // xT[j][r] = x0[rowBase+r][j]
  const int t = threadIdx.x;
  const int lane = t & 63, w = t >> 6;
  const int strip = blockIdx.x >> 1;
  const int cs_idx = blockIdx.x & 1, cs = cs_idx * 64;
  const int ii = w;
  const int rowBase = strip * 64;
  const int lr = lane & 15, lq = lane >> 4;

  for (int idx = t; idx < 26*64; idx += 256) {
    int j = idx >> 6, r = idx & 63;
    xT[j][r] = (float)xb[(rowBase + r)*32 + j];
  }

  // x1 slice in f32 registers: rows mi*16+lr, cols ii*32 + lq*8..+8
  float xf[4][8];
  #pragma unroll
  for (int mi = 0; mi < 4; ++mi) {
    bf16x8 xr = *(const bf16x8*)&x1b[(rowBase + mi*16 + lr)*128 + ii*32 + lq*8];
    #pragma unroll
    for (int e = 0; e < 8; ++e) xf[mi][e] = (float)xr[e];
  }

  f32x4 acc[4][4];
  #pragma unroll
  for (int mi=0; mi<4; ++mi)
    #pragma unroll
    for (int ni=0; ni<4; ++ni) acc[mi][ni] = {0.f,0.f,0.f,0.f};

  const bf16* tb = w2t + ((long)(cs_idx*4 + ii))*26*2048 + (lr*32 + lq*8); // + j*2048 + ni*512
  bf16x8 bc[4], bn[4];
  float scc[4], scn[4];
  #pragma unroll
  for (int ni=0; ni<4; ++ni) bc[ni] = *(const bf16x8*)(tb + ni*512);

  __syncthreads();
  #pragma unroll
  for (int mi=0; mi<4; ++mi) scc[mi] = xT[0][mi*16 + lr];

  for (int j = 0; j < 26; ++j) {
    if (j < 25) {
      #pragma unroll
      for (int ni=0; ni<4; ++ni) bn[ni] = *(const bf16x8*)(tb + (j+1)*2048 + ni*512);
      #pragma unroll
      for (int mi=0; mi<4; ++mi) scn[mi] = xT[j+1][mi*16 + lr];
    }
    bf16x8 af[4];
    #pragma unroll
    for (int mi=0; mi<4; ++mi)
      #pragma unroll
      for (int e=0; e<8; ++e) af[mi][e] = (bf16)(scc[mi] * xf[mi][e]);
    #pragma unroll
    for (int mi=0; mi<4; ++mi)
      #pragma unroll
      for (int ni=0; ni<4; ++ni)
        acc[mi][ni] = __builtin_amdgcn_mfma_f32_16x16x32_bf16(af[mi], bc[ni], acc[mi][ni], 0, 0, 0);
    #pragma unroll
    for (int ni=0; ni<4; ++ni) bc[ni] = bn[ni];
    #pragma unroll
    for (int mi=0; mi<4; ++mi) scc[mi] = scn[mi];
  }

  // partial k-sums to p2[ii][b][col]; 64 rows = 2 b's
  #pragma unroll
  for (int half=0; half<2; ++half) {
    int b = (rowBase >> 5) + half;
    #pragma unroll
    for (int ni=0; ni<4; ++ni) {
      float v = 0.f;
      #pragma unroll
      for (int mi=0; mi<2; ++mi)
        #pragma unroll
        for (int r=0; r<4; ++r) v += acc[half*2+mi][ni][r];
      v += __shfl_xor(v, 16, 64);
      v += __shfl_xor(v, 32, 64);
      if (lq == 0) p2[(ii*NB + b)*128 + cs + ni*16 + lr] = v;
    }
  }
}

// ---------------- combine: out[b][128+col] = sum_ii p2 + 32*b2 ----------------
__global__ __launch_bounds__(256) void combine(
    const float* __restrict__ p2, const float* __restrict__ b2, float* __restrict__ out)
{
  int idx = blockIdx.x * 256 + threadIdx.x;   // [0, NB*128)
  int b = idx >> 7, col = idx & 127;
  float v = 32.0f * b2[col];
  #pragma unroll
  for (int ii=0; ii<4; ++ii) v += p2[(ii*NB + b)*128 + col];
  out[b*256 + 128 + col] = v;
}

// ---------------- launch ----------------
extern "C" void kernel_launch(void* const* d_in, const int* in_sizes, int n_in,
                              void* d_out, int out_size, void* d_ws, size_t ws_size,
                              hipStream_t stream) {
  const float* in = (const float*)d_in[0];
  const float* W1 = (const float*)d_in[1];
  const float* b1 = (const float*)d_in[2];
  const float* W2 = (const float*)d_in[3];
  const float* b2 = (const float*)d_in[4];
  float* out = (float*)d_out;

  char* ws = (char*)d_ws;
  bf16*  xb  = (bf16*)(ws);               // 65536*32*2   = 4   MiB
  bf16*  w1t = (bf16*)(ws + 4194304);     // 2*26*2048*2  = 208 KiB
  bf16*  w2t = (bf16*)(ws + 4407296);     // 8*26*2048*2  = 832 KiB
  bf16*  x1b = (bf16*)(ws + 5259264);     // 65536*128*2  = 16  MiB
  float* p2  = (float*)(ws + 22036480);   // 4*2048*128*4 = 4   MiB

  prep_x  <<<NROWS*32/256,    256, 0, stream>>>(in, xb);
  prep_w1t<<<2*26*2048/256,   256, 0, stream>>>(W1, w1t);
  prep_w2t<<<8*26*2048/256,   256, 0, stream>>>(W2, w2t);
  cin1    <<<512,             256, 0, stream>>>(xb, w1t, b1, x1b, out);
  cin2    <<<2048,            256, 0, stream>>>(xb, x1b, w2t, p2);
  combine <<<NB*128/256,      256, 0, stream>>>(p2, b2, out);
}